// Round 4
// baseline (796.725 us; speedup 1.0000x reference)
//
#include <hip/hip_runtime.h>
#include <math.h>

// FreqProj: out[b][c] = mean_j( f[b][c][j].re*cos(ph) - f[b][c][j].im*sin(ph) )
// ph = (2*pi/F)*(x[b]·k[:,j]); k recomputed on the fly from linspace meshgrid.
//
// ROUND 4 = RESUBMIT of round 3's measurement (round 3 hit a GPU-acquisition
// timeout; never ran). zero+main are bitwise identical to round 2 (passed,
// absmax 0). The (zero, main) pair is launched TWICE; only the second pair
// determines the output, so correctness is unchanged. dur_us(this) -
// dur_us(round2=690) ~= one zero+main pass:
//   +~90 us  => main at read roofline (~6 TB/s)  => done with main.
//   +~175 us => main ~2x off roofline            => attack the read path.

#define NF       1024
#define NF2      (NF * NF)
#define NB       32
#define CHUNKS   64          // blocks per batch
#define THREADS  256
#define STRD     (CHUNKS * THREADS)   // 16384 float4s between per-thread elements

__global__ __launch_bounds__(64) void freqproj_zero(float* out) {
    out[threadIdx.x] = 0.0f;   // d_out poisoned with 0xAA before every launch
}

__device__ __forceinline__ void fp_term(const float4 a, const float4 c, int e,
                                        float x0, float x1,
                                        float& acc0, float& acc1)
{
    constexpr float PHC     = (float)(2.0 * 3.14159265359 / (double)NF);
    constexpr float INV1023 = 1.0f / 1023.0f;
    const int j0 = e << 1;
    const int jc = j0 & (NF - 1);
    const float krow = (float)(j0 >> 10) * INV1023;
    const float kA   = (float)jc        * INV1023;
    const float kB   = (float)(jc + 1)  * INV1023;
    const float base = x0 * krow;
    const float ph0  = PHC * fmaf(x1, kA, base);
    const float ph1  = PHC * fmaf(x1, kB, base);
    float sn0, cs0, sn1, cs1;
    __sincosf(ph0, &sn0, &cs0);
    __sincosf(ph1, &sn1, &cs1);
    acc0 += a.x * cs0 - a.y * sn0 + a.z * cs1 - a.w * sn1;
    acc1 += c.x * cs0 - c.y * sn0 + c.z * cs1 - c.w * sn1;
}

__global__ __launch_bounds__(THREADS) void freqproj_main(
        const float4* __restrict__ f,   // [B][2][F^2][2] fp32 viewed as float4
        const float*  __restrict__ x,   // [B][2]
        float*        __restrict__ out) // [B][2]
{
    const int b  = blockIdx.y;
    const float x0 = x[2 * b];
    const float x1 = x[2 * b + 1];

    const float4* __restrict__ f0 = f + (size_t)(2 * b) * (NF2 / 2);
    const float4* __restrict__ f1 = f0 + (NF2 / 2);

    constexpr float INVF2 = 1.0f / (float)NF2;

    float acc0 = 0.0f, acc1 = 0.0f;
    int e = blockIdx.x * THREADS + threadIdx.x;   // [0, 16384)

    #pragma unroll
    for (int it = 0; it < 8; ++it) {
        const float4 a0 = f0[e];
        const float4 a1 = f0[e +     STRD];
        const float4 a2 = f0[e + 2 * STRD];
        const float4 a3 = f0[e + 3 * STRD];
        const float4 c0 = f1[e];
        const float4 c1 = f1[e +     STRD];
        const float4 c2 = f1[e + 2 * STRD];
        const float4 c3 = f1[e + 3 * STRD];
        fp_term(a0, c0, e,            x0, x1, acc0, acc1);
        fp_term(a1, c1, e +     STRD, x0, x1, acc0, acc1);
        fp_term(a2, c2, e + 2 * STRD, x0, x1, acc0, acc1);
        fp_term(a3, c3, e + 3 * STRD, x0, x1, acc0, acc1);
        e += 4 * STRD;
    }

    for (int off = 32; off > 0; off >>= 1) {
        acc0 += __shfl_down(acc0, off);
        acc1 += __shfl_down(acc1, off);
    }

    __shared__ float red0[THREADS / 64];
    __shared__ float red1[THREADS / 64];
    const int wave = threadIdx.x >> 6;
    if ((threadIdx.x & 63) == 0) { red0[wave] = acc0; red1[wave] = acc1; }
    __syncthreads();

    if (threadIdx.x == 0) {
        float t0 = red0[0] + red0[1] + red0[2] + red0[3];
        float t1 = red1[0] + red1[1] + red1[2] + red1[3];
        atomicAdd(&out[2 * b],     t0 * INVF2);
        atomicAdd(&out[2 * b + 1], t1 * INVF2);
    }
}

extern "C" void kernel_launch(void* const* d_in, const int* in_sizes, int n_in,
                              void* d_out, int out_size, void* d_ws, size_t ws_size,
                              hipStream_t stream) {
    const float4* f = (const float4*)d_in[0];  // [32,2,F^2,2] fp32
    const float*  x = (const float*)d_in[1];   // [32,2]
    float* out = (float*)d_out;                // [32,2] fp32

    dim3 grid(CHUNKS, NB);

    // Ballast pair (timing probe): result fully overwritten by second pair.
    freqproj_zero<<<1, 64, 0, stream>>>(out);
    freqproj_main<<<grid, THREADS, 0, stream>>>(f, x, out);

    // Real pair: determines the final output.
    freqproj_zero<<<1, 64, 0, stream>>>(out);
    freqproj_main<<<grid, THREADS, 0, stream>>>(f, x, out);
}

// Round 5
// 675.070 us; speedup vs baseline: 1.1802x; 1.1802x over previous
//
#include <hip/hip_runtime.h>
#include <math.h>

// FreqProj: out[b][c] = mean_j( f[b][c][j].re*cos(ph) - f[b][c][j].im*sin(ph) )
// ph = (2*pi/F)*(x[b]·k[:,j]); k recomputed on the fly from linspace meshgrid.
//
// ROUND 5: (a) REVERT round-4's ballast probe (it cost +106 us; probe showed
// main ~90-103 us ~= 5.2-6.0 TB/s read, i.e. 85-95% of the 6.3 TB/s ceiling).
// (b) ONE variable vs round 2: block-CONTIGUOUS traversal instead of
// grid-strided. Each block now owns a contiguous 128 KB slab per channel
// (wave-contiguous 1 KB per load, 4 KB per unroll step) instead of 4 KB
// granules strided 256 KB apart -> ~4K sequential DRAM streams chip-wide
// instead of ~16K. Per-element math, trig sharing, and 8-deep load
// pipelining unchanged.

#define NF       1024
#define NF2      (NF * NF)
#define NB       32
#define CHUNKS   64          // blocks per batch
#define THREADS  256
#define BLK_F4   (NF2 / 2 / CHUNKS)   // 8192 float4s per block per channel

__global__ __launch_bounds__(64) void freqproj_zero(float* out) {
    out[threadIdx.x] = 0.0f;   // d_out poisoned with 0xAA before every launch
}

__device__ __forceinline__ void fp_term(const float4 a, const float4 c, int e,
                                        float x0, float x1,
                                        float& acc0, float& acc1)
{
    constexpr float PHC     = (float)(2.0 * 3.14159265359 / (double)NF);
    constexpr float INV1023 = 1.0f / 1023.0f;
    const int j0 = e << 1;
    const int jc = j0 & (NF - 1);
    const float krow = (float)(j0 >> 10) * INV1023;
    const float kA   = (float)jc        * INV1023;
    const float kB   = (float)(jc + 1)  * INV1023;
    const float base = x0 * krow;
    const float ph0  = PHC * fmaf(x1, kA, base);
    const float ph1  = PHC * fmaf(x1, kB, base);
    float sn0, cs0, sn1, cs1;
    __sincosf(ph0, &sn0, &cs0);
    __sincosf(ph1, &sn1, &cs1);
    acc0 += a.x * cs0 - a.y * sn0 + a.z * cs1 - a.w * sn1;
    acc1 += c.x * cs0 - c.y * sn0 + c.z * cs1 - c.w * sn1;
}

__global__ __launch_bounds__(THREADS) void freqproj_main(
        const float4* __restrict__ f,   // [B][2][F^2][2] fp32 viewed as float4
        const float*  __restrict__ x,   // [B][2]
        float*        __restrict__ out) // [B][2]
{
    const int b  = blockIdx.y;
    const float x0 = x[2 * b];
    const float x1 = x[2 * b + 1];

    const float4* __restrict__ f0 = f + (size_t)(2 * b) * (NF2 / 2);
    const float4* __restrict__ f1 = f0 + (NF2 / 2);

    constexpr float INVF2 = 1.0f / (float)NF2;

    float acc0 = 0.0f, acc1 = 0.0f;
    const int base = blockIdx.x * BLK_F4 + threadIdx.x;  // contiguous 128KB slab/block

    // 32 float4 per thread per channel = 8 iterations x unroll-4,
    // contiguous 4 KB steps within the block's slab.
    #pragma unroll
    for (int it = 0; it < 8; ++it) {
        const int e0 = base + it * (4 * THREADS);
        // Issue all 8 loads before any use: 8 KB per wave in flight.
        const float4 a0 = f0[e0];
        const float4 a1 = f0[e0 +     THREADS];
        const float4 a2 = f0[e0 + 2 * THREADS];
        const float4 a3 = f0[e0 + 3 * THREADS];
        const float4 c0 = f1[e0];
        const float4 c1 = f1[e0 +     THREADS];
        const float4 c2 = f1[e0 + 2 * THREADS];
        const float4 c3 = f1[e0 + 3 * THREADS];
        fp_term(a0, c0, e0,               x0, x1, acc0, acc1);
        fp_term(a1, c1, e0 +     THREADS, x0, x1, acc0, acc1);
        fp_term(a2, c2, e0 + 2 * THREADS, x0, x1, acc0, acc1);
        fp_term(a3, c3, e0 + 3 * THREADS, x0, x1, acc0, acc1);
    }

    // wave64 butterfly reduce
    for (int off = 32; off > 0; off >>= 1) {
        acc0 += __shfl_down(acc0, off);
        acc1 += __shfl_down(acc1, off);
    }

    __shared__ float red0[THREADS / 64];
    __shared__ float red1[THREADS / 64];
    const int wave = threadIdx.x >> 6;
    if ((threadIdx.x & 63) == 0) { red0[wave] = acc0; red1[wave] = acc1; }
    __syncthreads();

    if (threadIdx.x == 0) {
        float t0 = red0[0] + red0[1] + red0[2] + red0[3];
        float t1 = red1[0] + red1[1] + red1[2] + red1[3];
        atomicAdd(&out[2 * b],     t0 * INVF2);
        atomicAdd(&out[2 * b + 1], t1 * INVF2);
    }
}

extern "C" void kernel_launch(void* const* d_in, const int* in_sizes, int n_in,
                              void* d_out, int out_size, void* d_ws, size_t ws_size,
                              hipStream_t stream) {
    const float4* f = (const float4*)d_in[0];  // [32,2,F^2,2] fp32
    const float*  x = (const float*)d_in[1];   // [32,2]
    float* out = (float*)d_out;                // [32,2] fp32

    freqproj_zero<<<1, 64, 0, stream>>>(out);
    dim3 grid(CHUNKS, NB);
    freqproj_main<<<grid, THREADS, 0, stream>>>(f, x, out);
}